// Round 3
// baseline (431.962 us; speedup 1.0000x reference)
//
#include <hip/hip_runtime.h>
#include <hip/hip_bf16.h>
#include <stdint.h>

typedef __bf16 bf16_t;
typedef __attribute__((ext_vector_type(8))) __bf16 bf16x8;
typedef __attribute__((ext_vector_type(4))) float f32x4;
typedef __attribute__((ext_vector_type(8))) unsigned short u16x8;

#define S_LEN 2048
#define DIM   4096
#define QKVN  6144
#define NHEAD 32
#define HDIM  128

typedef __attribute__((address_space(1))) unsigned int as1_u32;
typedef __attribute__((address_space(3))) unsigned int as3_u32;

__device__ __forceinline__ unsigned short f2bf(float f) {
  unsigned u = __builtin_bit_cast(unsigned, f);
  u += 0x7fffu + ((u >> 16) & 1u);
  return (unsigned short)(u >> 16);
}

__device__ __forceinline__ void gload_lds16(const void* g, void* l) {
  __builtin_amdgcn_global_load_lds(
      (as1_u32*)(unsigned long long)(uintptr_t)g,
      (as3_u32*)(unsigned int)(uintptr_t)l,
      16, 0, 0);
}

__global__ __launch_bounds__(256) void cvt_kernel(const float* __restrict__ in,
                                                  unsigned short* __restrict__ out,
                                                  int n4) {
  int idx = blockIdx.x * 256 + threadIdx.x;
  int stride = gridDim.x * 256;
  for (int i = idx; i < n4; i += stride) {
    float4 v = ((const float4*)in)[i];
    ushort4 o;
    o.x = f2bf(v.x); o.y = f2bf(v.y); o.z = f2bf(v.z); o.w = f2bf(v.w);
    ((ushort4*)out)[i] = o;
  }
}

// ---------------- 256x256 pipelined GEMM, BK=32, 8 waves ----------------
// C(M,N) = A(M,K) * B(N,K)^T. LDS 64KB: 2 buffers x (A 256x32 + B 256x32).
// T2: linear LDS dest + source-slot XOR(row&3) + same XOR on read.
// T3/T4: phase-split K-loop, counted vmcnt(2) — loads span barriers.
// T5: setprio around MFMA clusters. T1: XCD-bijective block swizzle.
__device__ __forceinline__ void stage_tile(const bf16_t* __restrict__ g, int ldk,
                                           long rowBase, int k0, char* ldsBase,
                                           int tid) {
#pragma unroll
  for (int i = 0; i < 2; ++i) {
    int c = tid + i * 512;
    int row = c >> 2, slot = c & 3;
    const bf16_t* src = g + (rowBase + row) * (long)ldk + k0 + ((slot ^ (row & 3)) << 3);
    gload_lds16(src, ldsBase + c * 16);
  }
}

__device__ __forceinline__ bf16x8 frag_ld(const char* base, int row, int lg) {
  return *(const bf16x8*)(base + row * 64 + ((lg ^ (row & 3)) << 4));
}

template <int OUTF32>
__global__ __launch_bounds__(512, 2) void gemm256(const bf16_t* __restrict__ A,
                                                  const bf16_t* __restrict__ B,
                                                  void* __restrict__ Cout,
                                                  int M, int N, int K, int nxt) {
  __shared__ char lds[65536];
  const int tid = threadIdx.x;
  const int lane = tid & 63, w = tid >> 6;
  const int wm = w >> 2, wn = w & 3;     // 2 M-waves x 4 N-waves
  const int lg = lane >> 4, lr = lane & 15;
  const int nwg = gridDim.x;
  const int orig = blockIdx.x;
  const int wgid = (orig & 7) * (nwg >> 3) + (orig >> 3);  // nwg % 8 == 0
  const int bx = wgid % nxt, by = wgid / nxt;
  const long rowA = (long)by * 256;
  const long rowB = (long)bx * 256;

  f32x4 acc[8][4];
  const f32x4 z4 = {0.f, 0.f, 0.f, 0.f};
#pragma unroll
  for (int i = 0; i < 8; ++i)
#pragma unroll
    for (int j = 0; j < 4; ++j) acc[i][j] = z4;

  // prologue: stage K-tiles 0 and 1; wait tile 0 only (A1,B1 stay in flight)
  stage_tile(A, K, rowA, 0, lds, tid);
  stage_tile(B, K, rowB, 0, lds + 16384, tid);
  stage_tile(A, K, rowA, 32, lds + 32768, tid);
  stage_tile(B, K, rowB, 32, lds + 49152, tid);
  asm volatile("s_waitcnt vmcnt(4)" ::: "memory");
  __builtin_amdgcn_s_barrier();

  const int nt = K >> 5;
  for (int t = 0; t < nt; ++t) {
    const char* Ab = lds + (t & 1) * 32768;
    const char* Bb = Ab + 16384;
    bf16x8 bfr[4], af[4];
    // ---- phase 1: read B(all) + A(mf0..3); stage A(t+1) ----
#pragma unroll
    for (int nf = 0; nf < 4; ++nf) bfr[nf] = frag_ld(Bb, wn * 64 + nf * 16 + lr, lg);
#pragma unroll
    for (int mf = 0; mf < 4; ++mf) af[mf] = frag_ld(Ab, wm * 128 + mf * 16 + lr, lg);
    if (t >= 1 && t + 1 < nt)
      stage_tile(A, K, rowA, (t + 1) * 32, lds + ((t + 1) & 1) * 32768, tid);
    asm volatile("" ::: "memory");
    __builtin_amdgcn_s_barrier();
    asm volatile("s_waitcnt lgkmcnt(0)" ::: "memory");
    __builtin_amdgcn_s_setprio(1);
#pragma unroll
    for (int mf = 0; mf < 4; ++mf)
#pragma unroll
      for (int nf = 0; nf < 4; ++nf)
        acc[mf][nf] = __builtin_amdgcn_mfma_f32_16x16x32_bf16(af[mf], bfr[nf],
                                                              acc[mf][nf], 0, 0, 0);
    __builtin_amdgcn_s_setprio(0);
    asm volatile("" ::: "memory");
    __builtin_amdgcn_s_barrier();
    // ---- phase 2: read A(mf4..7); stage B(t+2) into just-freed B region ----
#pragma unroll
    for (int mf = 0; mf < 4; ++mf)
      af[mf] = frag_ld(Ab, wm * 128 + (mf + 4) * 16 + lr, lg);
    if (t + 2 < nt) {
      stage_tile(B, K, rowB, (t + 2) * 32, lds + (t & 1) * 32768 + 16384, tid);
      asm volatile("s_waitcnt vmcnt(2)" ::: "memory");   // leave B(t+2) in flight
    } else {
      asm volatile("s_waitcnt vmcnt(0)" ::: "memory");
    }
    __builtin_amdgcn_s_barrier();
    asm volatile("s_waitcnt lgkmcnt(0)" ::: "memory");
    __builtin_amdgcn_s_setprio(1);
#pragma unroll
    for (int mf = 0; mf < 4; ++mf)
#pragma unroll
      for (int nf = 0; nf < 4; ++nf)
        acc[mf + 4][nf] = __builtin_amdgcn_mfma_f32_16x16x32_bf16(af[mf], bfr[nf],
                                                                  acc[mf + 4][nf], 0, 0, 0);
    __builtin_amdgcn_s_setprio(0);
    asm volatile("" ::: "memory");
    __builtin_amdgcn_s_barrier();
  }

  // epilogue: C(row, col), row = Arow, col = Brow (verified layout)
  if (OUTF32) {
    float* C = (float*)Cout;
#pragma unroll
    for (int mf = 0; mf < 8; ++mf)
#pragma unroll
      for (int j = 0; j < 4; ++j) {
        long row = rowA + wm * 128 + mf * 16 + lg * 4 + j;
        float* cp = C + row * N + rowB + wn * 64 + lr;
#pragma unroll
        for (int nf = 0; nf < 4; ++nf) cp[nf * 16] = acc[mf][nf][j];
      }
  } else {
    unsigned short* C = (unsigned short*)Cout;
#pragma unroll
    for (int mf = 0; mf < 8; ++mf)
#pragma unroll
      for (int j = 0; j < 4; ++j) {
        long row = rowA + wm * 128 + mf * 16 + lg * 4 + j;
        unsigned short* cp = C + row * N + rowB + wn * 64 + lr;
#pragma unroll
        for (int nf = 0; nf < 4; ++nf) cp[nf * 16] = f2bf(acc[mf][nf][j]);
      }
  }
}

// In-place RoPE on bf16 qkv buffer (q heads 0..31, k heads 32..39).
__global__ __launch_bounds__(256) void rope_kernel(unsigned int* __restrict__ qkv32,
                                                   const float* __restrict__ cosb,
                                                   const float* __restrict__ sinb) {
  int t = blockIdx.x * 256 + threadIdx.x;
  int i  = t & 63;
  int sh = t >> 6;
  int hh = sh % 40;
  int s  = sh / 40;
  int col2 = (hh < 32) ? (hh * 64 + i) : (2048 + (hh - 32) * 64 + i);
  unsigned int* p = qkv32 + (long)s * (QKVN / 2) + col2;
  unsigned int v = *p;
  float tr = __builtin_bit_cast(float, (v & 0xffffu) << 16);
  float ti = __builtin_bit_cast(float, v & 0xffff0000u);
  float c  = cosb[s * 64 + i];
  float sn = sinb[s * 64 + i];
  float orr = tr * c - ti * sn;
  float oi  = tr * sn + ti * c;
  *p = (unsigned int)f2bf(orr) | ((unsigned int)f2bf(oi) << 16);
}

// V transpose: vT[kh][hd][s] from qkv[s][5120 + kh*128 + hd].
__global__ __launch_bounds__(256) void vtrans_kernel(const bf16_t* __restrict__ qkv,
                                                     bf16_t* __restrict__ vT) {
  const int kh = blockIdx.x;
  const int hd = threadIdx.x & 127;
  const int s0 = blockIdx.y * 16 + (threadIdx.x >> 7) * 8;
  u16x8 v;
#pragma unroll
  for (int e = 0; e < 8; ++e)
    v[e] = *(const unsigned short*)(qkv + (long)(s0 + e) * QKVN + 5120 + kh * HDIM + hd);
  *(u16x8*)(vT + ((long)kh * HDIM + hd) * S_LEN + s0) = v;
}

// Flash attention: block = (64 q-rows, 1 head), 4 waves x 16 q-rows, KVBLK=64.
__global__ __launch_bounds__(256) void attn_kernel(const bf16_t* __restrict__ qkv,
                                                   const bf16_t* __restrict__ vT,
                                                   unsigned short* __restrict__ ob) {
  __shared__ bf16_t Kt[64 * 128];
  __shared__ bf16_t Vt[128 * 64];
  __shared__ bf16_t Pl[4 * 16 * 64];
  const int h  = blockIdx.x;
  const int qi = 31 - blockIdx.y;
  const int qb = qi * 64;
  const int kh = h >> 2;
  const int tid = threadIdx.x, lane = tid & 63, w = tid >> 6;
  const int lg = lane >> 4, lr = lane & 15;
  const int qrow0 = qb + w * 16;

  bf16x8 qf[4];
  const bf16_t* qptr = qkv + (long)(qrow0 + lr) * QKVN + h * HDIM + lg * 8;
#pragma unroll
  for (int kk = 0; kk < 4; ++kk) qf[kk] = *(const bf16x8*)(qptr + kk * 32);

  const f32x4 z4 = {0.f, 0.f, 0.f, 0.f};
  f32x4 oacc[8];
#pragma unroll
  for (int c = 0; c < 8; ++c) oacc[c] = z4;
  float m[4]    = {-1e30f, -1e30f, -1e30f, -1e30f};
  float lsum[4] = {0.f, 0.f, 0.f, 0.f};

  char* KtB = (char*)Kt;
  char* VtB = (char*)Vt;
  char* PlB = (char*)Pl + w * 2048;
  const float scale = 0.08838834764831845f;
  const int ntiles = qi + 1;

  for (int t = 0; t < ntiles; ++t) {
    const int kv0 = t * 64;
    __syncthreads();
#pragma unroll
    for (int it = 0; it < 4; ++it) {
      int cch = tid + it * 256;
      int r = cch >> 4, c = cch & 15;
      const bf16_t* src = qkv + (long)(kv0 + r) * QKVN + 4096 + kh * HDIM
                          + ((c ^ (r & 7)) * 8);
      gload_lds16(src, KtB + cch * 16);
    }
#pragma unroll
    for (int it = 0; it < 4; ++it) {
      int cch = tid + it * 256;
      int hd = cch >> 3, c = cch & 7;
      const bf16_t* src = vT + ((long)kh * HDIM + hd) * S_LEN + kv0
                          + ((c ^ (hd & 7)) * 8);
      gload_lds16(src, VtB + cch * 16);
    }
    __syncthreads();

    f32x4 sf[4];
#pragma unroll
    for (int f = 0; f < 4; ++f) {
      f32x4 a = z4;
      int n = f * 16 + lr;
      int rb = n * 256, sw = (n & 7) << 4;
#pragma unroll
      for (int kk = 0; kk < 4; ++kk) {
        bf16x8 kf = *(const bf16x8*)(KtB + rb + (((kk * 4 + lg) * 16) ^ sw));
        a = __builtin_amdgcn_mfma_f32_16x16x32_bf16(qf[kk], kf, a, 0, 0, 0);
      }
      sf[f] = a;
    }

    float sc_arr[4];
#pragma unroll
    for (int j = 0; j < 4; ++j) {
      int qrow = qrow0 + lg * 4 + j;
      float sv[4];
#pragma unroll
      for (int f = 0; f < 4; ++f) {
        float s = sf[f][j] * scale;
        if (kv0 + f * 16 + lr > qrow) s = -1e9f;
        sv[f] = s;
      }
      float mx = fmaxf(fmaxf(sv[0], sv[1]), fmaxf(sv[2], sv[3]));
      mx = fmaxf(mx, __shfl_xor(mx, 1));
      mx = fmaxf(mx, __shfl_xor(mx, 2));
      mx = fmaxf(mx, __shfl_xor(mx, 4));
      mx = fmaxf(mx, __shfl_xor(mx, 8));
      float mn = fmaxf(m[j], mx);
      float p[4];
#pragma unroll
      for (int f = 0; f < 4; ++f) p[f] = __expf(sv[f] - mn);
      float ps = (p[0] + p[1]) + (p[2] + p[3]);
      ps += __shfl_xor(ps, 1);
      ps += __shfl_xor(ps, 2);
      ps += __shfl_xor(ps, 4);
      ps += __shfl_xor(ps, 8);
      float sc = __expf(m[j] - mn);
      lsum[j] = lsum[j] * sc + ps;
      m[j] = mn;
      sc_arr[j] = sc;
      int row = lg * 4 + j;
      int swp = (row & 7) << 4;
#pragma unroll
      for (int f = 0; f < 4; ++f)
        *(unsigned short*)(PlB + row * 128 + (((f * 16 + lr) * 2) ^ swp)) = f2bf(p[f]);
    }
#pragma unroll
    for (int c = 0; c < 8; ++c)
#pragma unroll
      for (int j = 0; j < 4; ++j) oacc[c][j] *= sc_arr[j];

    bf16x8 pfr[2];
#pragma unroll
    for (int kk = 0; kk < 2; ++kk)
      pfr[kk] = *(const bf16x8*)(PlB + lr * 128 + (((kk * 4 + lg) * 16) ^ ((lr & 7) << 4)));
#pragma unroll
    for (int c = 0; c < 8; ++c) {
      int hd = c * 16 + lr;
      int rb = hd * 128, sw = (hd & 7) << 4;
#pragma unroll
      for (int kk = 0; kk < 2; ++kk) {
        bf16x8 vf = *(const bf16x8*)(VtB + rb + (((kk * 4 + lg) * 16) ^ sw));
        oacc[c] = __builtin_amdgcn_mfma_f32_16x16x32_bf16(pfr[kk], vf, oacc[c], 0, 0, 0);
      }
    }
  }

  float rl[4];
#pragma unroll
  for (int j = 0; j < 4; ++j) rl[j] = 1.f / lsum[j];
#pragma unroll
  for (int c = 0; c < 8; ++c)
#pragma unroll
    for (int j = 0; j < 4; ++j) {
      long row = qrow0 + lg * 4 + j;
      ob[row * 4096 + h * 128 + c * 16 + lr] = f2bf(oacc[c][j] * rl[j]);
    }
}

extern "C" void kernel_launch(void* const* d_in, const int* in_sizes, int n_in,
                              void* d_out, int out_size, void* d_ws, size_t ws_size,
                              hipStream_t stream) {
  const float* x  = (const float*)d_in[0];
  const float* wq = (const float*)d_in[1];
  const float* wk = (const float*)d_in[2];
  const float* wv = (const float*)d_in[3];
  const float* wo = (const float*)d_in[4];
  const float* fc = (const float*)d_in[5];
  const float* fs = (const float*)d_in[6];

  char* ws = (char*)d_ws;
  bf16_t* xb    = (bf16_t*)(ws + 0);          // 2048x4096 (dead after gemm1)
  bf16_t* wqkvb = (bf16_t*)(ws + 16777216);   // 6144x4096
  bf16_t* wob   = (bf16_t*)(ws + 67108864);   // 4096x4096
  bf16_t* qkv   = (bf16_t*)(ws + 100663296);  // 2048x6144
  bf16_t* ob    = (bf16_t*)(ws + 125829120);  // 2048x4096
  bf16_t* vT    = (bf16_t*)(ws + 0);          // 8x128x2048 (4 MB, reuses xb)

  cvt_kernel<<<2048, 256, 0, stream>>>(x,  (unsigned short*)xb,                    (2048 * 4096) / 4);
  cvt_kernel<<<2048, 256, 0, stream>>>(wq, (unsigned short*)wqkvb,                 (4096 * 4096) / 4);
  cvt_kernel<<<1024, 256, 0, stream>>>(wk, (unsigned short*)(wqkvb + 4096 * 4096), (1024 * 4096) / 4);
  cvt_kernel<<<1024, 256, 0, stream>>>(wv, (unsigned short*)(wqkvb + 5120 * 4096), (1024 * 4096) / 4);
  cvt_kernel<<<2048, 256, 0, stream>>>(wo, (unsigned short*)wob,                   (4096 * 4096) / 4);

  gemm256<0><<<192, 512, 0, stream>>>(xb, wqkvb, qkv, 2048, 6144, 4096, 24);
  vtrans_kernel<<<dim3(8, 128), 256, 0, stream>>>(qkv, vT);
  rope_kernel<<<20480, 256, 0, stream>>>((unsigned int*)qkv, fc, fs);
  attn_kernel<<<dim3(32, 32), 256, 0, stream>>>(qkv, vT, (unsigned short*)ob);
  gemm256<1><<<128, 512, 0, stream>>>(ob, wob, d_out, 2048, 4096, 4096, 16);
}

// Round 4
// 362.302 us; speedup vs baseline: 1.1923x; 1.1923x over previous
//
#include <hip/hip_runtime.h>
#include <hip/hip_bf16.h>
#include <stdint.h>

typedef __bf16 bf16_t;
typedef __attribute__((ext_vector_type(8))) __bf16 bf16x8;
typedef __attribute__((ext_vector_type(4))) float f32x4;
typedef __attribute__((ext_vector_type(8))) unsigned short u16x8;

#define S_LEN 2048
#define DIM   4096
#define QKVN  6144
#define NHEAD 32
#define HDIM  128

typedef __attribute__((address_space(1))) unsigned int as1_u32;
typedef __attribute__((address_space(3))) unsigned int as3_u32;

__device__ __forceinline__ unsigned short f2bf(float f) {
  unsigned u = __builtin_bit_cast(unsigned, f);
  u += 0x7fffu + ((u >> 16) & 1u);
  return (unsigned short)(u >> 16);
}

__device__ __forceinline__ void gload_lds16(const void* g, void* l) {
  __builtin_amdgcn_global_load_lds(
      (as1_u32*)(unsigned long long)(uintptr_t)g,
      (as3_u32*)(unsigned int)(uintptr_t)l,
      16, 0, 0);
}

__global__ __launch_bounds__(256) void cvt_kernel(const float* __restrict__ in,
                                                  unsigned short* __restrict__ out,
                                                  int n4) {
  int idx = blockIdx.x * 256 + threadIdx.x;
  int stride = gridDim.x * 256;
  for (int i = idx; i < n4; i += stride) {
    float4 v = ((const float4*)in)[i];
    ushort4 o;
    o.x = f2bf(v.x); o.y = f2bf(v.y); o.z = f2bf(v.z); o.w = f2bf(v.w);
    ((ushort4*)out)[i] = o;
  }
}

// ---------------- 256x128 pipelined GEMM, BK=32, 8 waves (4M x 2N) --------
// C(M,N) = A(M,K) * B(N,K)^T. LDS 48KB: 2 buffers x (A 256x32 + B 128x32).
// Swizzle key (row>>1)&3: ds_read_b128 lands 2 lanes/bank-quad (free).
// Counted vmcnt(3): staging loads span barriers; 2 K-tiles lookahead.
__device__ __forceinline__ void stage_A(const bf16_t* __restrict__ g, int ldk,
                                        long rowBase, int k0, char* ldsBase, int tid) {
#pragma unroll
  for (int i = 0; i < 2; ++i) {
    int c = tid + i * 512;
    int row = c >> 2, slot = c & 3;
    const bf16_t* src = g + (rowBase + row) * (long)ldk + k0
                        + ((slot ^ ((row >> 1) & 3)) << 3);
    gload_lds16(src, ldsBase + c * 16);
  }
}

__device__ __forceinline__ void stage_B(const bf16_t* __restrict__ g, int ldk,
                                        long rowBase, int k0, char* ldsBase, int tid) {
  int row = tid >> 2, slot = tid & 3;
  const bf16_t* src = g + (rowBase + row) * (long)ldk + k0
                      + ((slot ^ ((row >> 1) & 3)) << 3);
  gload_lds16(src, ldsBase + tid * 16);
}

__device__ __forceinline__ bf16x8 frag_ld(const char* base, int row, int lg) {
  return *(const bf16x8*)(base + row * 64 + ((lg ^ ((row >> 1) & 3)) << 4));
}

template <int OUTF32>
__global__ __launch_bounds__(512, 2) void gemm256(const bf16_t* __restrict__ A,
                                                  const bf16_t* __restrict__ B,
                                                  void* __restrict__ Cout,
                                                  int M, int N, int K, int nxt) {
  __shared__ char lds[49152];
  const int tid = threadIdx.x;
  const int lane = tid & 63, w = tid >> 6;
  const int wm = w >> 1, wn = w & 1;     // 4 M-waves x 2 N-waves, 64x64 each
  const int lg = lane >> 4, lr = lane & 15;
  const int nwg = gridDim.x;
  const int orig = blockIdx.x;
  const int wgid = (orig & 7) * (nwg >> 3) + (orig >> 3);  // nwg % 8 == 0
  const int bx = wgid % nxt, by = wgid / nxt;
  const long rowA = (long)by * 256;
  const long rowB = (long)bx * 128;

  f32x4 acc[4][4];
  const f32x4 z4 = {0.f, 0.f, 0.f, 0.f};
#pragma unroll
  for (int i = 0; i < 4; ++i)
#pragma unroll
    for (int j = 0; j < 4; ++j) acc[i][j] = z4;

  // prologue: stage K-tiles 0 and 1 (3 VMEM ops each); wait tile 0 only
  stage_A(A, K, rowA, 0, lds, tid);
  stage_B(B, K, rowB, 0, lds + 16384, tid);
  stage_A(A, K, rowA, 32, lds + 24576, tid);
  stage_B(B, K, rowB, 32, lds + 40960, tid);
  asm volatile("s_waitcnt vmcnt(3)" ::: "memory");
  __builtin_amdgcn_s_barrier();

  const int nt = K >> 5;
  for (int t = 0; t < nt; ++t) {
    char* Ab = lds + (t & 1) * 24576;
    char* Bb = Ab + 16384;
    bf16x8 af[4], bfr[4];
#pragma unroll
    for (int mf = 0; mf < 4; ++mf) af[mf] = frag_ld(Ab, wm * 64 + mf * 16 + lr, lg);
#pragma unroll
    for (int nf = 0; nf < 4; ++nf) bfr[nf] = frag_ld(Bb, wn * 64 + nf * 16 + lr, lg);
    asm volatile("s_waitcnt lgkmcnt(0)" ::: "memory");
    __builtin_amdgcn_sched_barrier(0);
    __builtin_amdgcn_s_barrier();     // all waves' frags in regs; buffers free
    if (t + 2 < nt) {                 // stage t+2 into the buffer just consumed
      stage_A(A, K, rowA, (t + 2) * 32, Ab, tid);
      stage_B(B, K, rowB, (t + 2) * 32, Bb, tid);
    }
    __builtin_amdgcn_s_setprio(1);
#pragma unroll
    for (int mf = 0; mf < 4; ++mf)
#pragma unroll
      for (int nf = 0; nf < 4; ++nf)
        acc[mf][nf] = __builtin_amdgcn_mfma_f32_16x16x32_bf16(af[mf], bfr[nf],
                                                              acc[mf][nf], 0, 0, 0);
    __builtin_amdgcn_s_setprio(0);
    if (t + 2 < nt) {
      asm volatile("s_waitcnt vmcnt(3)" ::: "memory");  // t+1's stage complete
    } else {
      asm volatile("s_waitcnt vmcnt(0)" ::: "memory");
    }
    __builtin_amdgcn_s_barrier();     // next buffer ready for next step's reads
  }

  const long crow = rowA + wm * 64;
  const long ccol = rowB + wn * 64;
  if (OUTF32) {
    float* C = (float*)Cout;
#pragma unroll
    for (int mf = 0; mf < 4; ++mf)
#pragma unroll
      for (int j = 0; j < 4; ++j) {
        long row = crow + mf * 16 + lg * 4 + j;
        float* cp = C + row * N + ccol + lr;
#pragma unroll
        for (int nf = 0; nf < 4; ++nf) cp[nf * 16] = acc[mf][nf][j];
      }
  } else {
    unsigned short* C = (unsigned short*)Cout;
#pragma unroll
    for (int mf = 0; mf < 4; ++mf)
#pragma unroll
      for (int j = 0; j < 4; ++j) {
        long row = crow + mf * 16 + lg * 4 + j;
        unsigned short* cp = C + row * N + ccol + lr;
#pragma unroll
        for (int nf = 0; nf < 4; ++nf) cp[nf * 16] = f2bf(acc[mf][nf][j]);
      }
  }
}

// In-place RoPE on bf16 qkv buffer (q heads 0..31, k heads 32..39).
__global__ __launch_bounds__(256) void rope_kernel(unsigned int* __restrict__ qkv32,
                                                   const float* __restrict__ cosb,
                                                   const float* __restrict__ sinb) {
  int t = blockIdx.x * 256 + threadIdx.x;
  int i  = t & 63;
  int sh = t >> 6;
  int hh = sh % 40;
  int s  = sh / 40;
  int col2 = (hh < 32) ? (hh * 64 + i) : (2048 + (hh - 32) * 64 + i);
  unsigned int* p = qkv32 + (long)s * (QKVN / 2) + col2;
  unsigned int v = *p;
  float tr = __builtin_bit_cast(float, (v & 0xffffu) << 16);
  float ti = __builtin_bit_cast(float, v & 0xffff0000u);
  float c  = cosb[s * 64 + i];
  float sn = sinb[s * 64 + i];
  float orr = tr * c - ti * sn;
  float oi  = tr * sn + ti * c;
  *p = (unsigned int)f2bf(orr) | ((unsigned int)f2bf(oi) << 16);
}

// V transpose: vT[kh][hd][s] from qkv[s][5120 + kh*128 + hd].
__global__ __launch_bounds__(256) void vtrans_kernel(const bf16_t* __restrict__ qkv,
                                                     bf16_t* __restrict__ vT) {
  const int kh = blockIdx.x;
  const int hd = threadIdx.x & 127;
  const int s0 = blockIdx.y * 16 + (threadIdx.x >> 7) * 8;
  u16x8 v;
#pragma unroll
  for (int e = 0; e < 8; ++e)
    v[e] = *(const unsigned short*)(qkv + (long)(s0 + e) * QKVN + 5120 + kh * HDIM + hd);
  *(u16x8*)(vT + ((long)kh * HDIM + hd) * S_LEN + s0) = v;
}

// Flash attention: block = (64 q-rows, 1 head), 4 waves x 16 q-rows, KVBLK=64.
__global__ __launch_bounds__(256) void attn_kernel(const bf16_t* __restrict__ qkv,
                                                   const bf16_t* __restrict__ vT,
                                                   unsigned short* __restrict__ ob) {
  __shared__ bf16_t Kt[64 * 128];
  __shared__ bf16_t Vt[128 * 64];
  __shared__ bf16_t Pl[4 * 16 * 64];
  const int h  = blockIdx.x;
  const int qi = 31 - blockIdx.y;
  const int qb = qi * 64;
  const int kh = h >> 2;
  const int tid = threadIdx.x, lane = tid & 63, w = tid >> 6;
  const int lg = lane >> 4, lr = lane & 15;
  const int qrow0 = qb + w * 16;

  bf16x8 qf[4];
  const bf16_t* qptr = qkv + (long)(qrow0 + lr) * QKVN + h * HDIM + lg * 8;
#pragma unroll
  for (int kk = 0; kk < 4; ++kk) qf[kk] = *(const bf16x8*)(qptr + kk * 32);

  const f32x4 z4 = {0.f, 0.f, 0.f, 0.f};
  f32x4 oacc[8];
#pragma unroll
  for (int c = 0; c < 8; ++c) oacc[c] = z4;
  float m[4]    = {-1e30f, -1e30f, -1e30f, -1e30f};
  float lsum[4] = {0.f, 0.f, 0.f, 0.f};

  char* KtB = (char*)Kt;
  char* VtB = (char*)Vt;
  char* PlB = (char*)Pl + w * 2048;
  const float scale = 0.08838834764831845f;
  const int ntiles = qi + 1;

  for (int t = 0; t < ntiles; ++t) {
    const int kv0 = t * 64;
    __syncthreads();
#pragma unroll
    for (int it = 0; it < 4; ++it) {
      int cch = tid + it * 256;
      int r = cch >> 4, c = cch & 15;
      const bf16_t* src = qkv + (long)(kv0 + r) * QKVN + 4096 + kh * HDIM
                          + ((c ^ (r & 7)) * 8);
      gload_lds16(src, KtB + cch * 16);
    }
#pragma unroll
    for (int it = 0; it < 4; ++it) {
      int cch = tid + it * 256;
      int hd = cch >> 3, c = cch & 7;
      const bf16_t* src = vT + ((long)kh * HDIM + hd) * S_LEN + kv0
                          + ((c ^ (hd & 7)) * 8);
      gload_lds16(src, VtB + cch * 16);
    }
    __syncthreads();

    f32x4 sf[4];
#pragma unroll
    for (int f = 0; f < 4; ++f) {
      f32x4 a = z4;
      int n = f * 16 + lr;
      int rb = n * 256, sw = (n & 7) << 4;
#pragma unroll
      for (int kk = 0; kk < 4; ++kk) {
        bf16x8 kf = *(const bf16x8*)(KtB + rb + (((kk * 4 + lg) * 16) ^ sw));
        a = __builtin_amdgcn_mfma_f32_16x16x32_bf16(qf[kk], kf, a, 0, 0, 0);
      }
      sf[f] = a;
    }

    float sc_arr[4];
#pragma unroll
    for (int j = 0; j < 4; ++j) {
      int qrow = qrow0 + lg * 4 + j;
      float sv[4];
#pragma unroll
      for (int f = 0; f < 4; ++f) {
        float s = sf[f][j] * scale;
        if (kv0 + f * 16 + lr > qrow) s = -1e9f;
        sv[f] = s;
      }
      float mx = fmaxf(fmaxf(sv[0], sv[1]), fmaxf(sv[2], sv[3]));
      mx = fmaxf(mx, __shfl_xor(mx, 1));
      mx = fmaxf(mx, __shfl_xor(mx, 2));
      mx = fmaxf(mx, __shfl_xor(mx, 4));
      mx = fmaxf(mx, __shfl_xor(mx, 8));
      float mn = fmaxf(m[j], mx);
      float p[4];
#pragma unroll
      for (int f = 0; f < 4; ++f) p[f] = __expf(sv[f] - mn);
      float ps = (p[0] + p[1]) + (p[2] + p[3]);
      ps += __shfl_xor(ps, 1);
      ps += __shfl_xor(ps, 2);
      ps += __shfl_xor(ps, 4);
      ps += __shfl_xor(ps, 8);
      float sc = __expf(m[j] - mn);
      lsum[j] = lsum[j] * sc + ps;
      m[j] = mn;
      sc_arr[j] = sc;
      int row = lg * 4 + j;
      int swp = (row & 7) << 4;
#pragma unroll
      for (int f = 0; f < 4; ++f)
        *(unsigned short*)(PlB + row * 128 + (((f * 16 + lr) * 2) ^ swp)) = f2bf(p[f]);
    }
#pragma unroll
    for (int c = 0; c < 8; ++c)
#pragma unroll
      for (int j = 0; j < 4; ++j) oacc[c][j] *= sc_arr[j];

    bf16x8 pfr[2];
#pragma unroll
    for (int kk = 0; kk < 2; ++kk)
      pfr[kk] = *(const bf16x8*)(PlB + lr * 128 + (((kk * 4 + lg) * 16) ^ ((lr & 7) << 4)));
#pragma unroll
    for (int c = 0; c < 8; ++c) {
      int hd = c * 16 + lr;
      int rb = hd * 128, sw = (hd & 7) << 4;
#pragma unroll
      for (int kk = 0; kk < 2; ++kk) {
        bf16x8 vf = *(const bf16x8*)(VtB + rb + (((kk * 4 + lg) * 16) ^ sw));
        oacc[c] = __builtin_amdgcn_mfma_f32_16x16x32_bf16(pfr[kk], vf, oacc[c], 0, 0, 0);
      }
    }
  }

  float rl[4];
#pragma unroll
  for (int j = 0; j < 4; ++j) rl[j] = 1.f / lsum[j];
#pragma unroll
  for (int c = 0; c < 8; ++c)
#pragma unroll
    for (int j = 0; j < 4; ++j) {
      long row = qrow0 + lg * 4 + j;
      ob[row * 4096 + h * 128 + c * 16 + lr] = f2bf(oacc[c][j] * rl[j]);
    }
}

extern "C" void kernel_launch(void* const* d_in, const int* in_sizes, int n_in,
                              void* d_out, int out_size, void* d_ws, size_t ws_size,
                              hipStream_t stream) {
  const float* x  = (const float*)d_in[0];
  const float* wq = (const float*)d_in[1];
  const float* wk = (const float*)d_in[2];
  const float* wv = (const float*)d_in[3];
  const float* wo = (const float*)d_in[4];
  const float* fc = (const float*)d_in[5];
  const float* fs = (const float*)d_in[6];

  char* ws = (char*)d_ws;
  bf16_t* xb    = (bf16_t*)(ws + 0);          // 2048x4096 (dead after gemm1)
  bf16_t* wqkvb = (bf16_t*)(ws + 16777216);   // 6144x4096
  bf16_t* wob   = (bf16_t*)(ws + 67108864);   // 4096x4096
  bf16_t* qkv   = (bf16_t*)(ws + 100663296);  // 2048x6144
  bf16_t* ob    = (bf16_t*)(ws + 125829120);  // 2048x4096
  bf16_t* vT    = (bf16_t*)(ws + 0);          // 8x128x2048 (4 MB, reuses xb)

  cvt_kernel<<<2048, 256, 0, stream>>>(x,  (unsigned short*)xb,                    (2048 * 4096) / 4);
  cvt_kernel<<<2048, 256, 0, stream>>>(wq, (unsigned short*)wqkvb,                 (4096 * 4096) / 4);
  cvt_kernel<<<1024, 256, 0, stream>>>(wk, (unsigned short*)(wqkvb + 4096 * 4096), (1024 * 4096) / 4);
  cvt_kernel<<<1024, 256, 0, stream>>>(wv, (unsigned short*)(wqkvb + 5120 * 4096), (1024 * 4096) / 4);
  cvt_kernel<<<2048, 256, 0, stream>>>(wo, (unsigned short*)wob,                   (4096 * 4096) / 4);

  gemm256<0><<<384, 512, 0, stream>>>(xb, wqkvb, qkv, 2048, 6144, 4096, 48);
  vtrans_kernel<<<dim3(8, 128), 256, 0, stream>>>(qkv, vT);
  rope_kernel<<<20480, 256, 0, stream>>>((unsigned int*)qkv, fc, fs);
  attn_kernel<<<dim3(32, 32), 256, 0, stream>>>(qkv, vT, (unsigned short*)ob);
  gemm256<1><<<256, 512, 0, stream>>>(ob, wob, d_out, 2048, 4096, 4096, 32);
}